// Round 1
// 236.763 us; speedup vs baseline: 1.0871x; 1.0871x over previous
//
#include <hip/hip_runtime.h>
#include <cmath>

#define S_LEN 2048
#define EMB   1024
#define NHEAD 16
#define DHEAD 64
#define PIT   72   // LDS pitch (ushorts): 144B = 16B-aligned, worst 2-way bank alias (free per m136)

typedef __attribute__((ext_vector_type(8))) short bf16x8;
typedef __attribute__((ext_vector_type(4))) float f32x4;

__device__ __forceinline__ unsigned short f2bf(float f){
    union { float f; unsigned u; } v; v.f = f;
    unsigned r = v.u + 0x7fffu + ((v.u >> 16) & 1u);
    return (unsigned short)(r >> 16);
}

__device__ __forceinline__ unsigned pk2bf(float a, float b){
#if __has_builtin(__builtin_amdgcn_cvt_pk_bf16_f32)
    typedef __attribute__((ext_vector_type(2))) __bf16 bf2;
    bf2 r = __builtin_amdgcn_cvt_pk_bf16_f32(a, b);
    return *(unsigned*)&r;
#else
    return (unsigned)f2bf(a) | ((unsigned)f2bf(b) << 16);
#endif
}

__device__ __forceinline__ float fast_exp2(float x){
#if __has_builtin(__builtin_amdgcn_exp2f)
    return __builtin_amdgcn_exp2f(x);
#else
    return exp2f(x);
#endif
}

__device__ __forceinline__ float fast_rcp(float x){
#if __has_builtin(__builtin_amdgcn_rcpf)
    return __builtin_amdgcn_rcpf(x);
#else
    return 1.0f / x;
#endif
}

// ---------------- fused prep: range-dispatched over blockIdx.x ----------------
// [0,4096):     Q (prescaled exp2-domain) + K -> bf16 [N,H,S,D]
// [4096,5120):  V -> bf16 transposed [N,H,D,S]
// [5120,6144):  W -> bf16
// [6144,7168):  mask int32 -> 1 BIT per element, Mb[n][q][k/32] uint32 (1 MB total, L2-resident)
// (zero-init range removed: split-K now writes disjoint buffers with plain stores, no atomics)
__global__ void prep_all(const float* __restrict__ q, const float* __restrict__ k,
                         const float* __restrict__ v, const int* __restrict__ mask,
                         const float* __restrict__ W,
                         unsigned short* __restrict__ Qb, unsigned short* __restrict__ Kb,
                         unsigned short* __restrict__ Vt, unsigned short* __restrict__ Wb,
                         unsigned* __restrict__ Mb){
    __shared__ unsigned short tile[64*68];
    const int b = blockIdx.x, tid = threadIdx.x;
    if (b < 4096){
        const float SC = 0.045084220027780106f;   // log2(e)/32
        int base = (b*256 + tid) * 4;
        int e = base & (EMB - 1);
        int s = (base >> 10) & (S_LEN - 1);
        int n = base >> 21;
        int h = e >> 6, d = e & 63;
        int dst = ((n*NHEAD + h)*S_LEN + s)*DHEAD + d;
        float4 qv = *(const float4*)(q + base);
        float4 kv = *(const float4*)(k + base);
        uint2 qp, kp;
        qp.x = pk2bf(qv.x*SC, qv.y*SC);
        qp.y = pk2bf(qv.z*SC, qv.w*SC);
        kp.x = pk2bf(kv.x, kv.y);
        kp.y = pk2bf(kv.z, kv.w);
        *(uint2*)(Qb + dst) = qp;
        *(uint2*)(Kb + dst) = kp;
    } else if (b < 5120){
        int idx = b - 4096;
        int st = idx & 31, h = (idx >> 5) & 15, n = idx >> 9;
        int sbase = st * 64;
#pragma unroll
        for (int i = 0; i < 4; i++){
            int c = tid + i*256;
            int srow = c >> 4, c4 = (c & 15) * 4;
            float4 x = *(const float4*)(v + (n*S_LEN + sbase + srow)*EMB + h*DHEAD + c4);
            uint2 p;
            p.x = pk2bf(x.x, x.y);
            p.y = pk2bf(x.z, x.w);
            *(uint2*)&tile[srow*68 + c4] = p;
        }
        __syncthreads();
#pragma unroll
        for (int i = 0; i < 2; i++){
            int c = tid + i*256;
            int d = c >> 3, s8 = (c & 7) * 8;
            unsigned u0 = (unsigned)tile[(s8+0)*68 + d] | ((unsigned)tile[(s8+1)*68 + d] << 16);
            unsigned u1 = (unsigned)tile[(s8+2)*68 + d] | ((unsigned)tile[(s8+3)*68 + d] << 16);
            unsigned u2 = (unsigned)tile[(s8+4)*68 + d] | ((unsigned)tile[(s8+5)*68 + d] << 16);
            unsigned u3 = (unsigned)tile[(s8+6)*68 + d] | ((unsigned)tile[(s8+7)*68 + d] << 16);
            uint4 pk; pk.x = u0; pk.y = u1; pk.z = u2; pk.w = u3;
            *(uint4*)(Vt + ((n*NHEAD + h)*DHEAD + d)*S_LEN + sbase + s8) = pk;
        }
    } else if (b < 6144){
        int base = ((b - 5120)*256 + tid) * 4;
        float4 x = *(const float4*)(W + base);
        uint2 p;
        p.x = pk2bf(x.x, x.y);
        p.y = pk2bf(x.z, x.w);
        *(uint2*)(Wb + base) = p;
    } else {
        // bit-pack: thread u builds one uint32 from 32 consecutive mask ints (128 B read)
        int u = (b - 6144)*256 + tid;                 // [0, 262144)
        const int4* m4 = (const int4*)mask + (size_t)u*8;
        unsigned w = 0;
#pragma unroll
        for (int i = 0; i < 8; i++){
            int4 m = m4[i];
            unsigned nib = (m.x ? 1u : 0u) | (m.y ? 2u : 0u) | (m.z ? 4u : 0u) | (m.w ? 8u : 0u);
            w |= nib << (i*4);
        }
        Mb[u] = w;
    }
}

// ---------------- flash attention, E^T layout, fixed-max softmax, split-K=2 ----------------
// grid (16,32,2) remapped in-kernel so the 16 qt-blocks sharing a (n,h,split) K/V slice land
// on the SAME XCD (K/V/mask slices become L2-local instead of 8x-duplicated via L3).
// Mask is 1 bit/element (L2-resident 1 MB), expanded per (rt,t) via a 16-entry LDS LUT
// (16 distinct b64 addrs -> 16 distinct bank pairs: conflict-free, duplicates broadcast).
// Split-K partials now go to disjoint Op0/Op1 with plain stores: no atomics, no zero-init.
__global__ __launch_bounds__(256, 4) void flash_attn(
    const unsigned short* __restrict__ Qb, const unsigned short* __restrict__ Kb,
    const unsigned short* __restrict__ Vt, const unsigned* __restrict__ Mb,
    float* __restrict__ Op, float* __restrict__ Lp){
    __shared__ unsigned short Kt[64*PIT];
    __shared__ unsigned short Vl[64*PIT];
    __shared__ unsigned short Pt[4][32*PIT];
    __shared__ uint2 mlut[16];

    const int tid = threadIdx.x;
    if (tid < 16){
        uint2 e;
        e.x = ((tid & 1) ? 0xFFFFu : 0u) | ((tid & 2) ? 0xFFFF0000u : 0u);
        e.y = ((tid & 4) ? 0xFFFFu : 0u) | ((tid & 8) ? 0xFFFF0000u : 0u);
        mlut[tid] = e;
    }

    // XCD-aware remap: flat -> (xcd, idx); slice = xcd + 8*(idx>>4) so each XCD owns
    // 8 full (n,h,split) slices x 16 qt-blocks (1024 % 8 == 0: bijective).
    const int flat = blockIdx.x + (blockIdx.y << 4) + (blockIdx.z << 9);
    const int xcd = flat & 7, idx = flat >> 3;
    const int qt = idx & 15;
    const int sl = xcd + ((idx >> 4) << 3);           // [0,64)
    const int h = sl & 15, split = (sl >> 4) & 1, n = sl >> 5;

    const int wave = tid >> 6, lane = tid & 63, il = lane & 15, quad = lane >> 4;
    const int qbase = qt*128 + wave*32;
    const int kbase = split*1024;

    const unsigned short* Qh = Qb + (n*NHEAD + h)*S_LEN*DHEAD;
    const unsigned short* Kh = Kb + (n*NHEAD + h)*S_LEN*DHEAD + kbase*DHEAD;
    const unsigned short* Vh = Vt + (n*NHEAD + h)*DHEAD*S_LEN + kbase;
    const unsigned* mr0 = Mb + (size_t)(n*S_LEN + qbase + il)*(S_LEN/32) + (kbase >> 5);
    const unsigned* mr1 = mr0 + 16*(S_LEN/32);
    Op += (size_t)split * (2*S_LEN*EMB);              // split partial buffers are contiguous
    Lp += split * (2*NHEAD*S_LEN);

    // staging chunk owned by this thread (row r and r+32, 8 cols at c8)
    const int srow = tid >> 3, scol = (tid & 7)*8;

    bf16x8 Qf[2][2];   // B-operand frags: n=il -> q row, k = quad*8+j -> d
#pragma unroll
    for (int rt = 0; rt < 2; rt++)
#pragma unroll
        for (int ks = 0; ks < 2; ks++)
            Qf[rt][ks] = *(const bf16x8*)(Qh + (qbase + rt*16 + il)*DHEAD + ks*32 + quad*8);

    f32x4 acc[2][4], accL[2];
#pragma unroll
    for (int rt = 0; rt < 2; rt++){
        accL[rt] = (f32x4){0.f,0.f,0.f,0.f};
#pragma unroll
        for (int j = 0; j < 4; j++) acc[rt][j] = (f32x4){0.f,0.f,0.f,0.f};
    }
    const short onev = 0x3F80;   // bf16 1.0
    const bf16x8 onesb = {onev,onev,onev,onev,onev,onev,onev,onev};

    unsigned short* Pw = Pt[wave];
    const int q4 = quad*4;

    // prefetch tile 0 into registers
    uint4 kpre0 = *(const uint4*)(Kh + srow*DHEAD + scol);
    uint4 kpre1 = *(const uint4*)(Kh + (srow + 32)*DHEAD + scol);
    uint4 vpre0 = *(const uint4*)(Vh + srow*S_LEN + scol);
    uint4 vpre1 = *(const uint4*)(Vh + (srow + 32)*S_LEN + scol);

    for (int kb = 0; kb < 1024; kb += 64){
        // drain prefetch regs into LDS
        *(uint4*)&Kt[srow*PIT + scol]        = kpre0;
        *(uint4*)&Kt[(srow + 32)*PIT + scol] = kpre1;
        *(uint4*)&Vl[srow*PIT + scol]        = vpre0;
        *(uint4*)&Vl[(srow + 32)*PIT + scol] = vpre1;
        __syncthreads();
        // mask bits for this 64-wide k-tile: 2 words per q-row, L2-resident
        uint2 w0 = *(const uint2*)(mr0 + (kb >> 5));
        uint2 w1 = *(const uint2*)(mr1 + (kb >> 5));
        // issue next tile's loads; they land during this iter's compute
        if (kb + 64 < 1024){
            kpre0 = *(const uint4*)(Kh + (kb + 64 + srow)*DHEAD + scol);
            kpre1 = *(const uint4*)(Kh + (kb + 64 + srow + 32)*DHEAD + scol);
            vpre0 = *(const uint4*)(Vh + srow*S_LEN + kb + 64 + scol);
            vpre1 = *(const uint4*)(Vh + (srow + 32)*S_LEN + kb + 64 + scol);
        }

        // E^T = K.Q^T : A = K rows, B = Q rows. C: col=il -> q, row=quad*4+r -> k
        f32x4 e[2][4];
#pragma unroll
        for (int t = 0; t < 4; t++){
            bf16x8 kf0 = *(const bf16x8*)(&Kt[(t*16 + il)*PIT + quad*8]);
            bf16x8 kf1 = *(const bf16x8*)(&Kt[(t*16 + il)*PIT + 32 + quad*8]);
#pragma unroll
            for (int rt = 0; rt < 2; rt++){
                f32x4 z = (f32x4){0.f,0.f,0.f,0.f};
                z        = __builtin_amdgcn_mfma_f32_16x16x32_bf16(kf0, Qf[rt][0], z, 0, 0, 0);
                e[rt][t] = __builtin_amdgcn_mfma_f32_16x16x32_bf16(kf1, Qf[rt][1], z, 0, 0, 0);
            }
        }
        // p = exp2(e); mask applied as AND on packed bf16 pairs (x*{1,0} == x&{0xFFFF,0})
        // bit for (t,quad,r) = bit ((t&1)*16 + quad*4 + r) of word (t>>1)
#pragma unroll
        for (int rt = 0; rt < 2; rt++){
            const uint2 w = rt ? w1 : w0;
            unsigned s0 = w.x >> q4, s1 = w.y >> q4;
            unsigned s0h = s0 >> 16, s1h = s1 >> 16;
#pragma unroll
            for (int t = 0; t < 4; t++){
                unsigned s = (t == 0) ? s0 : (t == 1) ? s0h : (t == 2) ? s1 : s1h;
                uint2 mw = mlut[s & 0xFu];
                float p0 = fast_exp2(e[rt][t][0]);
                float p1 = fast_exp2(e[rt][t][1]);
                float p2 = fast_exp2(e[rt][t][2]);
                float p3 = fast_exp2(e[rt][t][3]);
                uint2 pk;
                pk.x = pk2bf(p0, p1) & mw.x;
                pk.y = pk2bf(p2, p3) & mw.y;
                *(uint2*)&Pw[(rt*16 + il)*PIT + t*16 + quad*4] = pk;
            }
        }
        // PV: O += P.V ; l += P.1 (MFMA with B=ones)
#pragma unroll
        for (int kk = 0; kk < 2; kk++){
            bf16x8 Pa[2];
#pragma unroll
            for (int rt = 0; rt < 2; rt++){
                Pa[rt] = *(const bf16x8*)(&Pw[(rt*16 + il)*PIT + kk*32 + quad*8]);
                accL[rt] = __builtin_amdgcn_mfma_f32_16x16x32_bf16(Pa[rt], onesb, accL[rt], 0, 0, 0);
            }
#pragma unroll
            for (int dt = 0; dt < 4; dt++){
                bf16x8 Vf = *(const bf16x8*)(&Vl[(dt*16 + il)*PIT + kk*32 + quad*8]);
#pragma unroll
                for (int rt = 0; rt < 2; rt++)
                    acc[rt][dt] = __builtin_amdgcn_mfma_f32_16x16x32_bf16(Pa[rt], Vf, acc[rt][dt], 0, 0, 0);
            }
        }
        __syncthreads();
    }

    // epilogue: plain stores of this split's unnormalized O partial + l partial
#pragma unroll
    for (int rt = 0; rt < 2; rt++){
#pragma unroll
        for (int dt = 0; dt < 4; dt++)
#pragma unroll
            for (int r = 0; r < 4; r++){
                size_t row = (size_t)(n*S_LEN + qbase + rt*16 + quad*4 + r);
                Op[row*EMB + h*DHEAD + dt*16 + il] = acc[rt][dt][r];
            }
        if (il == 0){
#pragma unroll
            for (int r = 0; r < 4; r++)
                Lp[(n*NHEAD + h)*S_LEN + qbase + rt*16 + quad*4 + r] = accL[rt][r];
        }
    }
}

// ---------------- fused normalize + output GEMM: out = ((Op0+Op1)/l).W^T + b ----------------
// 128M x 64N tiles, BK=64 (aligned to head dim so h = kb>>6 is iter-constant).
// XCD-aware remap: the 16 nb-blocks sharing an mb (same 512 KB Op slice) land on one XCD,
// so the slice is fetched from HBM/L3 once per XCD instead of 16x (was 69.5 MB FETCH).
// A-staging reads BOTH split partials, sums, multiplies by rcp(l0+l1), packs bf16 on the fly.
__global__ __launch_bounds__(256, 2) void gemm_norm(
    const float* __restrict__ Op0, const float* __restrict__ Op1,
    const float* __restrict__ Lp0, const float* __restrict__ Lp1,
    const unsigned short* __restrict__ W, const float* __restrict__ bias,
    float* __restrict__ out){
    __shared__ unsigned short At[128*PIT];
    __shared__ unsigned short Wt[64*PIT];
    const int flat = blockIdx.x + (blockIdx.y << 4);  // [0,512)
    const int xcd = flat & 7, idx = flat >> 3;
    const int nb = idx & 15, mb = xcd*4 + (idx >> 4); // bijective: 8 XCD x 4 mb x 16 nb
    const int tid = threadIdx.x;
    const int wave = tid >> 6, lane = tid & 63, il = lane & 15, quad = lane >> 4;
    const int wm = wave & 1, wn = wave >> 1;
    const int mbase = mb*128, nbase = nb*64;
    const int arow = tid >> 3, acol = (tid & 7)*8;   // A chunks: rows arow+{0,32,64,96}
    const int n_blk = mbase >> 11, qoff = (mbase & (S_LEN-1));
    const float* La = Lp0 + n_blk*NHEAD*S_LEN + qoff;
    const float* Lb = Lp1 + n_blk*NHEAD*S_LEN + qoff;

    f32x4 acc[4][2];
#pragma unroll
    for (int i = 0; i < 4; i++)
#pragma unroll
        for (int j = 0; j < 2; j++) acc[i][j] = (f32x4){0.f,0.f,0.f,0.f};

    float4 apre[4][2], bpre[4][2]; float lpa[4], lpb[4]; uint4 wpre[2];
    // prefetch kb=0
#pragma unroll
    for (int j = 0; j < 4; j++){
        size_t off = (size_t)(mbase + arow + j*32)*EMB + acol;
        apre[j][0] = *(const float4*)(Op0 + off);
        apre[j][1] = *(const float4*)(Op0 + off + 4);
        bpre[j][0] = *(const float4*)(Op1 + off);
        bpre[j][1] = *(const float4*)(Op1 + off + 4);
        lpa[j] = La[arow + j*32];                    // h = 0 at kb = 0
        lpb[j] = Lb[arow + j*32];
    }
#pragma unroll
    for (int j = 0; j < 2; j++)
        wpre[j] = *(const uint4*)(W + (size_t)(nbase + arow + j*32)*EMB + acol);

    for (int kb = 0; kb < EMB; kb += 64){
        // drain prefetch into LDS (A: sum splits + normalize + pack to bf16)
#pragma unroll
        for (int j = 0; j < 4; j++){
            float inv = fast_rcp(lpa[j] + lpb[j]);
            uint4 pk;
            pk.x = pk2bf((apre[j][0].x + bpre[j][0].x)*inv, (apre[j][0].y + bpre[j][0].y)*inv);
            pk.y = pk2bf((apre[j][0].z + bpre[j][0].z)*inv, (apre[j][0].w + bpre[j][0].w)*inv);
            pk.z = pk2bf((apre[j][1].x + bpre[j][1].x)*inv, (apre[j][1].y + bpre[j][1].y)*inv);
            pk.w = pk2bf((apre[j][1].z + bpre[j][1].z)*inv, (apre[j][1].w + bpre[j][1].w)*inv);
            *(uint4*)&At[(arow + j*32)*PIT + acol] = pk;
        }
#pragma unroll
        for (int j = 0; j < 2; j++)
            *(uint4*)&Wt[(arow + j*32)*PIT + acol] = wpre[j];
        __syncthreads();
        if (kb + 64 < EMB){
            int h = (kb + 64) >> 6;
#pragma unroll
            for (int j = 0; j < 4; j++){
                size_t off = (size_t)(mbase + arow + j*32)*EMB + kb + 64 + acol;
                apre[j][0] = *(const float4*)(Op0 + off);
                apre[j][1] = *(const float4*)(Op0 + off + 4);
                bpre[j][0] = *(const float4*)(Op1 + off);
                bpre[j][1] = *(const float4*)(Op1 + off + 4);
                lpa[j] = La[h*S_LEN + arow + j*32];
                lpb[j] = Lb[h*S_LEN + arow + j*32];
            }
#pragma unroll
            for (int j = 0; j < 2; j++)
                wpre[j] = *(const uint4*)(W + (size_t)(nbase + arow + j*32)*EMB + kb + 64 + acol);
        }
#pragma unroll
        for (int ks = 0; ks < 2; ks++){
            bf16x8 Af[4], Wf[2];
#pragma unroll
            for (int mt = 0; mt < 4; mt++)
                Af[mt] = *(const bf16x8*)(&At[(wm*64 + mt*16 + il)*PIT + ks*32 + quad*8]);
#pragma unroll
            for (int nt = 0; nt < 2; nt++)
                Wf[nt] = *(const bf16x8*)(&Wt[(wn*32 + nt*16 + il)*PIT + ks*32 + quad*8]);
#pragma unroll
            for (int mt = 0; mt < 4; mt++)
#pragma unroll
                for (int nt = 0; nt < 2; nt++)
                    acc[mt][nt] = __builtin_amdgcn_mfma_f32_16x16x32_bf16(Af[mt], Wf[nt], acc[mt][nt], 0, 0, 0);
        }
        __syncthreads();
    }
    float bb[2];
#pragma unroll
    for (int nt = 0; nt < 2; nt++) bb[nt] = bias[nbase + wn*32 + nt*16 + il];
#pragma unroll
    for (int mt = 0; mt < 4; mt++)
#pragma unroll
        for (int nt = 0; nt < 2; nt++)
#pragma unroll
            for (int r = 0; r < 4; r++){
                int row = mbase + wm*64 + mt*16 + quad*4 + r;
                int col = nbase + wn*32 + nt*16 + il;
                out[(size_t)row*EMB + col] = acc[mt][nt][r] + bb[nt];
            }
}

extern "C" void kernel_launch(void* const* d_in, const int* in_sizes, int n_in,
                              void* d_out, int out_size, void* d_ws, size_t ws_size,
                              hipStream_t stream){
    const float* values = (const float*)d_in[0];
    const float* keys   = (const float*)d_in[1];
    const float* query  = (const float*)d_in[2];
    const int*   mask   = (const int*)d_in[3];
    const float* W_fc   = (const float*)d_in[4];
    const float* b_fc   = (const float*)d_in[5];
    float* out = (float*)d_out;

    char* ws = (char*)d_ws;
    unsigned short* Qb  = (unsigned short*)(ws);                        // 8 MiB
    unsigned short* Kb  = (unsigned short*)(ws + (8ull  << 20));        // 8 MiB
    unsigned short* Vtb = (unsigned short*)(ws + (16ull << 20));        // 8 MiB
    unsigned short* Wb  = (unsigned short*)(ws + (24ull << 20));        // 2 MiB
    unsigned*       Mb  = (unsigned*)      (ws + (26ull << 20));        // 1 MiB (bit-packed mask)
    float*          Op0 = (float*)         (ws + (27ull << 20));        // 16 MiB split-0 O partial
    float*          Op1 = (float*)         (ws + (43ull << 20));        // 16 MiB split-1 O partial
    float*          Lp0 = (float*)         (ws + (59ull << 20));        // 256 KiB
    float*          Lp1 = (float*)         (ws + (59ull << 20) + (256ull << 10)); // -> 59.5 MiB

    prep_all  <<<7168, 256, 0, stream>>>(query, keys, values, mask, W_fc,
                                         Qb, Kb, Vtb, Wb, Mb);
    flash_attn<<<dim3(16, 32, 2), 256, 0, stream>>>(Qb, Kb, Vtb, Mb, Op0, Lp0);
    gemm_norm <<<dim3(16, 32), 256, 0, stream>>>(Op0, Op1, Lp0, Lp1, Wb, b_fc, out);
}